// Round 3
// baseline (382.595 us; speedup 1.0000x reference)
//
#include <hip/hip_runtime.h>
#include <hip/hip_bf16.h>

#define kB 16
#define kS 2048
#define kD 1024
#define kH 128
#define kBS (kB * kS)

typedef short s8v __attribute__((ext_vector_type(8)));
typedef float f4v __attribute__((ext_vector_type(4)));
typedef float f16v __attribute__((ext_vector_type(16)));
typedef unsigned short us4 __attribute__((ext_vector_type(4)));
typedef unsigned short us8 __attribute__((ext_vector_type(8)));

__device__ __forceinline__ unsigned short f2bf(float f) {
    __hip_bfloat16 h = __float2bfloat16(f);
    return __builtin_bit_cast(unsigned short, h);
}

// ---------------------------------------------------------------------------
// zero helper: p[0..n4) float4 = 0
// ---------------------------------------------------------------------------
__global__ void zero_f(float* __restrict__ p, int n4) {
    int i = blockIdx.x * 256 + threadIdx.x;
    if (i < n4) { f4v z = {0.f, 0.f, 0.f, 0.f}; *(f4v*)(p + (size_t)i * 4) = z; }
}

// ---------------------------------------------------------------------------
// Kernel 0: W[1024][128] fp32 -> Wt[g][128][1024] bf16 (transposed).
// Wq pre-scaled by H^-0.5.
// ---------------------------------------------------------------------------
__global__ void prep_w(const float* __restrict__ Wq, const float* __restrict__ Wk,
                       const float* __restrict__ Wv, unsigned short* __restrict__ Wt)
{
    const int g = blockIdx.x;
    const float* W = (g == 0) ? Wq : (g == 1) ? Wk : Wv;
    const float sc = (g == 0) ? 0.08838834764831845f : 1.0f;  // 128^-0.5 folded into Wq
    unsigned short* o = Wt + (size_t)g * 128 * 1024;
    const int t = threadIdx.x;
    const int n = t & 127;
    const int half = t >> 7;
    const int kbase = blockIdx.y * 64 + half * 32;
    #pragma unroll
    for (int c = 0; c < 4; ++c) {
        int kb = kbase + c * 8;
        us8 v;
        #pragma unroll
        for (int j = 0; j < 8; ++j) v[j] = f2bf(W[(size_t)(kb + j) * kH + n] * sc);
        *(us8*)(o + (size_t)n * 1024 + kb) = v;
    }
}

// ---------------------------------------------------------------------------
// Kernel 1: QKV GEMM. X[32768,1024] fp32 @ Wt[g][128][1024] bf16 -> qkv bf16.
// 128x128 tile / block, BK=64 (32 MFMA per barrier pair), padded LDS stride 72.
// ---------------------------------------------------------------------------
__global__ __launch_bounds__(256, 3) void qkv_gemm(
    const float* __restrict__ X, const unsigned short* __restrict__ Wt,
    unsigned short* __restrict__ ws)
{
    __shared__ unsigned short Xs[128 * 72];   // 128 x 64 bf16, stride 72 (2-way reads only)
    __shared__ unsigned short Bs[128 * 72];

    const int t    = threadIdx.x;
    const int L    = t & 63;
    const int w    = t >> 6;
    const int col  = L & 15;
    const int quad = L >> 4;
    const int g    = blockIdx.x;
    const int m0   = blockIdx.y * 128;
    const int rb   = (w >> 1) * 64, cb = (w & 1) * 64;
    const unsigned short* Wg = Wt + (size_t)g * 128 * 1024;

    f4v acc[4][4];
    #pragma unroll
    for (int i = 0; i < 4; ++i)
        #pragma unroll
        for (int j = 0; j < 4; ++j) { f4v z = {0.f, 0.f, 0.f, 0.f}; acc[i][j] = z; }

    const int ac4 = (t & 15) * 4;   // A: k-col (float4 granule)
    const int ar  = t >> 4;         // A: row base 0..15
    const int bc8 = (t & 7) * 8;    // B: k-col (us8 granule)
    const int bn  = t >> 3;         // B: n base 0..31

    for (int kk = 0; kk < kD / 64; ++kk) {
        const int k0 = kk * 64;
        __syncthreads();
        // stage A: 128x64 fp32 -> bf16. per instr: 4 rows x 256B contiguous.
        #pragma unroll
        for (int i = 0; i < 8; ++i) {
            float4 x = *(const float4*)(X + (size_t)(m0 + ar + i * 16) * kD + k0 + ac4);
            us4 bv = { f2bf(x.x), f2bf(x.y), f2bf(x.z), f2bf(x.w) };
            *(us4*)&Xs[(ar + i * 16) * 72 + ac4] = bv;
        }
        // stage B: bf16 copy. per instr: 8 rows x 128B contiguous.
        #pragma unroll
        for (int i = 0; i < 4; ++i) {
            us8 v = *(const us8*)(Wg + (size_t)(bn + i * 32) * kD + k0 + bc8);
            *(us8*)&Bs[(bn + i * 32) * 72 + bc8] = v;
        }
        __syncthreads();
        // 32 MFMA per wave (2 k-halves x 16)
        #pragma unroll
        for (int kh = 0; kh < 2; ++kh) {
            s8v Af[4], Bf[4];
            #pragma unroll
            for (int i = 0; i < 4; ++i)
                Af[i] = *(const s8v*)&Xs[(rb + i * 16 + col) * 72 + kh * 32 + quad * 8];
            #pragma unroll
            for (int j = 0; j < 4; ++j)
                Bf[j] = *(const s8v*)&Bs[(cb + j * 16 + col) * 72 + kh * 32 + quad * 8];
            #pragma unroll
            for (int i = 0; i < 4; ++i)
                #pragma unroll
                for (int j = 0; j < 4; ++j)
                    acc[i][j] = __builtin_amdgcn_mfma_f32_16x16x32_bf16(Af[i], Bf[j], acc[i][j], 0, 0, 0);
        }
    }
    // epilogue: C/D layout col=lane&15, row=quad*4+reg (HW-verified)
    unsigned short* outp = ws + (size_t)g * kBS * kH;
    #pragma unroll
    for (int i = 0; i < 4; ++i)
        #pragma unroll
        for (int j = 0; j < 4; ++j)
            #pragma unroll
            for (int rg = 0; rg < 4; ++rg) {
                int m = m0 + rb + i * 16 + quad * 4 + rg;
                int n = cb + j * 16 + col;
                outp[(size_t)m * kH + n] = f2bf(acc[i][j][rg]);
            }
}

// ---------------------------------------------------------------------------
// Kernel 2: causal attention, streaming softmax, split-K.
// q-tile = 128 rows; 4 waves each own 32 rows x all 128 h (no combine).
// Key-chunks of 512 (8 x 64-key tiles) -> 40 blocks/batch, atomicAdd partial
// O into d_out and l into lbuf; normalize kernel divides at the end.
// 32x32x16 MFMA. Q + O in registers; K from global (L2-hot); V swizzled LDS.
// ---------------------------------------------------------------------------
__global__ __launch_bounds__(256, 2) void attn(
    const unsigned short* __restrict__ ws, float* __restrict__ outacc,
    float* __restrict__ lbuf)
{
    __shared__ unsigned short Vt[128 * 72];      // V^T, k-dim XOR-swizzled by (h>>3)&7
    __shared__ unsigned short Ps[4 * 32 * 72];   // per-wave P (32 x 64)

    const int t   = threadIdx.x;
    const int L   = t & 63;
    const int w   = t >> 6;
    const int l5  = L >> 5;
    const int c32 = L & 31;
    const int b   = blockIdx.y;
    const int id  = 39 - (int)blockIdx.x;        // heavy chunks dispatched first

    int qt, ch;
    if (id < 4)       { qt = id;                 ch = 0; }
    else if (id < 12) { qt = 4 + (id - 4) / 2;   ch = (id - 4) & 1; }
    else if (id < 24) { qt = 8 + (id - 12) / 3;  ch = (id - 12) % 3; }
    else              { qt = 12 + ((id - 24) >> 2); ch = (id - 24) & 3; }

    const int q0     = qt << 7;
    const int jbeg   = ch * 8;
    const int jend   = min(jbeg + 8, 2 * qt + 2);
    const int rowmin = q0 + w * 32;
    const int rowmax = rowmin + 31;

    const unsigned short* qp = ws + (size_t)b * kS * kH;
    const unsigned short* kp = ws + (size_t)kBS * kH + (size_t)b * kS * kH;
    const unsigned short* vp = ws + (size_t)2 * kBS * kH + (size_t)b * kS * kH;

    // Q fragments (A-layout: m=lane&31, k=(lane>>5)*8+j) — verified in R2
    s8v Qf[8];
    #pragma unroll
    for (int ks = 0; ks < 8; ++ks)
        Qf[ks] = *(const s8v*)(qp + (size_t)(rowmin + c32) * kH + ks * 16 + l5 * 8);

    f16v O[4];
    float lsum[16];
    #pragma unroll
    for (int i = 0; i < 4; ++i)
        #pragma unroll
        for (int r = 0; r < 16; ++r) O[i][r] = 0.f;
    #pragma unroll
    for (int r = 0; r < 16; ++r) lsum[r] = 0.f;

    for (int j = jbeg; j < jend; ++j) {
        const int kb = j * 64;
        __syncthreads();
        // stage V^T with k-swizzle: V[key][h] -> Vt[h][ (key>>3 ^ (h>>3)&7)*8 + key&7 ]
        {
            int hc = t & 15, k4 = (t >> 4) * 4;
            us8 r0 = *(const us8*)(vp + (size_t)(kb + k4 + 0) * kH + hc * 8);
            us8 r1 = *(const us8*)(vp + (size_t)(kb + k4 + 1) * kH + hc * 8);
            us8 r2 = *(const us8*)(vp + (size_t)(kb + k4 + 2) * kH + hc * 8);
            us8 r3 = *(const us8*)(vp + (size_t)(kb + k4 + 3) * kH + hc * 8);
            int colbase = (((k4 >> 3) ^ (hc & 7)) << 3) + (k4 & 7);
            #pragma unroll
            for (int jj = 0; jj < 8; ++jj) {
                us4 pk = { r0[jj], r1[jj], r2[jj], r3[jj] };
                *(us4*)(Vt + (size_t)(hc * 8 + jj) * 72 + colbase) = pk;
            }
        }
        __syncthreads();

        int nvalid = rowmax - kb + 1;
        if (nvalid <= 0) continue;               // wave-uniform; barriers stay matched
        if (nvalid > 64) nvalid = 64;
        const int ngrp = (nvalid > 32) ? 2 : 1;

        #pragma unroll 2
        for (int g = 0; g < ngrp; ++g) {
            const int kb2 = kb + g * 32;
            // K B-frags (B-layout: n=lane&31, k=(lane>>5)*8+j) — verified in R2
            s8v Kf[8];
            #pragma unroll
            for (int ks = 0; ks < 8; ++ks)
                Kf[ks] = *(const s8v*)(kp + (size_t)(kb2 + c32) * kH + ks * 16 + l5 * 8);
            f16v Sv;
            #pragma unroll
            for (int r = 0; r < 16; ++r) Sv[r] = 0.f;
            #pragma unroll
            for (int ks = 0; ks < 8; ++ks)
                Sv = __builtin_amdgcn_mfma_f32_32x32x16_bf16(Qf[ks], Kf[ks], Sv, 0, 0, 0);

            const bool domask = (kb2 + 31 > rowmin);
            const int keyL = kb2 + c32;
            #pragma unroll
            for (int rg = 0; rg < 16; ++rg) {
                int row = (rg & 3) + 8 * (rg >> 2) + 4 * l5;   // local row 0..31
                float v = Sv[rg];
                if (domask && keyL > rowmin + row) v = -__builtin_inff();
                float e = __expf(v);
                lsum[rg] += e;
                Ps[(size_t)w * 2304 + (size_t)row * 72 + g * 32 + c32] = f2bf(e);
            }
        }

        // PV over valid 16-k blocks only (stale blocks excluded)
        const int nks = (nvalid + 15) >> 4;
        for (int ks = 0; ks < nks; ++ks) {
            s8v Pa = *(const s8v*)&Ps[(size_t)w * 2304 + (size_t)c32 * 72 + ks * 16 + l5 * 8];
            #pragma unroll
            for (int nt = 0; nt < 4; ++nt) {
                int h = nt * 32 + c32;
                int col = (((ks * 2 + l5) ^ ((h >> 3) & 7)) << 3);
                s8v Vb = *(const s8v*)(Vt + (size_t)h * 72 + col);
                O[nt] = __builtin_amdgcn_mfma_f32_32x32x16_bf16(Pa, Vb, O[nt], 0, 0, 0);
            }
        }
    }

    // reduce l across the 32-lane row group
    float lrow[16];
    #pragma unroll
    for (int rg = 0; rg < 16; ++rg) {
        float v = lsum[rg];
        v += __shfl_xor(v, 1, 32);
        v += __shfl_xor(v, 2, 32);
        v += __shfl_xor(v, 4, 32);
        v += __shfl_xor(v, 8, 32);
        v += __shfl_xor(v, 16, 32);
        lrow[rg] = v;
    }

    // additive split-K combine: atomicAdd partial O and l
    #pragma unroll
    for (int nt = 0; nt < 4; ++nt)
        #pragma unroll
        for (int rg = 0; rg < 16; ++rg) {
            int row = rowmin + (rg & 3) + 8 * (rg >> 2) + 4 * l5;
            atomicAdd(outacc + ((size_t)b * kS + row) * kH + nt * 32 + c32, O[nt][rg]);
        }
    if (c32 == 0) {
        #pragma unroll
        for (int rg = 0; rg < 16; ++rg) {
            int row = rowmin + (rg & 3) + 8 * (rg >> 2) + 4 * l5;
            atomicAdd(lbuf + (size_t)b * kS + row, lrow[rg]);
        }
    }
}

// ---------------------------------------------------------------------------
// Kernel 3: out = O_acc / l (row-broadcast divide)
// ---------------------------------------------------------------------------
__global__ void norm_k(float* __restrict__ out, const float* __restrict__ lbuf) {
    int i = blockIdx.x * 256 + threadIdx.x;       // float4 index, 32 per row
    float inv = 1.0f / lbuf[i >> 5];
    f4v x = *(f4v*)(out + (size_t)i * 4);
    x[0] *= inv; x[1] *= inv; x[2] *= inv; x[3] *= inv;
    *(f4v*)(out + (size_t)i * 4) = x;
}

extern "C" void kernel_launch(void* const* d_in, const int* in_sizes, int n_in,
                              void* d_out, int out_size, void* d_ws, size_t ws_size,
                              hipStream_t stream) {
    const float* X  = (const float*)d_in[0];
    const float* Wq = (const float*)d_in[1];
    const float* Wk = (const float*)d_in[2];
    const float* Wv = (const float*)d_in[3];
    unsigned short* ws = (unsigned short*)d_ws;              // q|k|v bf16 (25.2 MB)
    unsigned short* Wt = ws + (size_t)3 * kBS * kH;          // +786 KB transposed weights
    float* lbuf = (float*)(Wt + (size_t)3 * 128 * 1024);     // +128 KB row sums
    float* out = (float*)d_out;

    zero_f<<<dim3(kBS * kH / 4 / 256), 256, 0, stream>>>(out, kBS * kH / 4);
    zero_f<<<dim3(kBS / 4 / 256), 256, 0, stream>>>(lbuf, kBS / 4);
    prep_w<<<dim3(3, 16), 256, 0, stream>>>(Wq, Wk, Wv, Wt);
    qkv_gemm<<<dim3(3, 256), 256, 0, stream>>>(X, Wt, ws);
    attn<<<dim3(40, 16), 256, 0, stream>>>(ws, out, lbuf);
    norm_k<<<dim3(kBS * kH / 4 / 256), 256, 0, stream>>>(out, lbuf);
}

// Round 5
// 323.894 us; speedup vs baseline: 1.1812x; 1.1812x over previous
//
#include <hip/hip_runtime.h>
#include <hip/hip_bf16.h>

#define kB 16
#define kS 2048
#define kD 1024
#define kH 128
#define kBS (kB * kS)

typedef short s8v __attribute__((ext_vector_type(8)));
typedef float f4v __attribute__((ext_vector_type(4)));
typedef float f16v __attribute__((ext_vector_type(16)));
typedef unsigned short us4 __attribute__((ext_vector_type(4)));
typedef unsigned short us8 __attribute__((ext_vector_type(8)));

__device__ __forceinline__ unsigned short f2bf(float f) {
    __hip_bfloat16 h = __float2bfloat16(f);
    return __builtin_bit_cast(unsigned short, h);
}

// ---------------------------------------------------------------------------
// Kernel 0: W[1024][128] fp32 -> Wt[384][1024] bf16 (transposed, q|k|v).
// Wq pre-scaled by H^-0.5.  (unchanged from R4)
// ---------------------------------------------------------------------------
__global__ void prep_w(const float* __restrict__ Wq, const float* __restrict__ Wk,
                       const float* __restrict__ Wv, unsigned short* __restrict__ Wt)
{
    const int g = blockIdx.x;
    const float* W = (g == 0) ? Wq : (g == 1) ? Wk : Wv;
    const float sc = (g == 0) ? 0.08838834764831845f : 1.0f;  // 128^-0.5 folded into Wq
    unsigned short* o = Wt + (size_t)g * 128 * 1024;
    const int t = threadIdx.x;
    const int n = t & 127;
    const int half = t >> 7;
    const int kbase = blockIdx.y * 64 + half * 32;
    #pragma unroll
    for (int c = 0; c < 4; ++c) {
        int kb = kbase + c * 8;
        us8 v;
        #pragma unroll
        for (int j = 0; j < 8; ++j) v[j] = f2bf(W[(size_t)(kb + j) * kH + n] * sc);
        *(us8*)(o + (size_t)n * 1024 + kb) = v;
    }
}

// ---------------------------------------------------------------------------
// Kernel 1: fused QKV GEMM (unchanged from R4). X read ONCE; B from L2;
// q,k written [s][h]; v written TRANSPOSED [b][h][s].
// ---------------------------------------------------------------------------
__global__ __launch_bounds__(256, 2) void qkv_gemm(
    const float* __restrict__ X, const unsigned short* __restrict__ Wt,
    unsigned short* __restrict__ ws)
{
    __shared__ unsigned short smem[9216];   // Xs[64][136] bf16 | epilogue repack

    const int t    = threadIdx.x;
    const int L    = t & 63;
    const int w    = t >> 6;
    const int col  = L & 15;
    const int quad = L >> 4;
    const int m0   = blockIdx.x * 64;

    f4v acc[4][6];
    #pragma unroll
    for (int i = 0; i < 4; ++i)
        #pragma unroll
        for (int j = 0; j < 6; ++j) { f4v z = {0.f, 0.f, 0.f, 0.f}; acc[i][j] = z; }

    const int ar  = t >> 2;          // 0..63 staging row
    const int akc = (t & 3) * 32;    // 0..96 k-col base (floats)

    for (int kk = 0; kk < kD / 128; ++kk) {
        const int k0 = kk * 128;
        __syncthreads();
        float4 xv[8];
        #pragma unroll
        for (int u = 0; u < 8; ++u)
            xv[u] = *(const float4*)(X + (size_t)(m0 + ar) * kD + k0 + akc + u * 4);
        #pragma unroll
        for (int u2 = 0; u2 < 4; ++u2) {
            us8 pk;
            pk[0] = f2bf(xv[2*u2].x);   pk[1] = f2bf(xv[2*u2].y);
            pk[2] = f2bf(xv[2*u2].z);   pk[3] = f2bf(xv[2*u2].w);
            pk[4] = f2bf(xv[2*u2+1].x); pk[5] = f2bf(xv[2*u2+1].y);
            pk[6] = f2bf(xv[2*u2+1].z); pk[7] = f2bf(xv[2*u2+1].w);
            *(us8*)&smem[ar * 136 + akc + u2 * 8] = pk;
        }
        __syncthreads();
        #pragma unroll
        for (int ks = 0; ks < 4; ++ks) {
            s8v Af[4], Bf[6];
            #pragma unroll
            for (int i = 0; i < 4; ++i)
                Af[i] = *(const s8v*)&smem[(i * 16 + col) * 136 + ks * 32 + quad * 8];
            #pragma unroll
            for (int j = 0; j < 6; ++j) {
                int n = w * 96 + j * 16 + col;
                Bf[j] = *(const s8v*)(Wt + (size_t)n * kD + k0 + ks * 32 + quad * 8);
            }
            #pragma unroll
            for (int i = 0; i < 4; ++i)
                #pragma unroll
                for (int j = 0; j < 6; ++j)
                    acc[i][j] = __builtin_amdgcn_mfma_f32_16x16x32_bf16(Af[i], Bf[j], acc[i][j], 0, 0, 0);
        }
    }

    for (int g = 0; g < 3; ++g) {
        __syncthreads();
        #pragma unroll
        for (int j = 0; j < 6; ++j) {
            if (((96 * w + 16 * j) >> 7) != g) continue;   // wave-uniform
            int n = w * 96 + j * 16 + col;
            if (g < 2) {
                int ng = n - g * 128;
                #pragma unroll
                for (int i = 0; i < 4; ++i)
                    #pragma unroll
                    for (int rg = 0; rg < 4; ++rg)
                        smem[(i * 16 + quad * 4 + rg) * 136 + ng] = f2bf(acc[i][j][rg]);
            } else {
                int h = n - 256;
                #pragma unroll
                for (int i = 0; i < 4; ++i) {
                    us4 pk = { f2bf(acc[i][j][0]), f2bf(acc[i][j][1]),
                               f2bf(acc[i][j][2]), f2bf(acc[i][j][3]) };
                    *(us4*)&smem[h * 72 + i * 16 + quad * 4] = pk;   // Ts[h][s]
                }
            }
        }
        __syncthreads();
        if (g < 2) {
            unsigned short* outp = ws + (size_t)g * kBS * kH;
            int row = t >> 2, hc = (t & 3) * 32;
            #pragma unroll
            for (int u = 0; u < 4; ++u) {
                us8 v = *(const us8*)&smem[row * 136 + hc + u * 8];
                *(us8*)(outp + (size_t)(m0 + row) * kH + hc + u * 8) = v;
            }
        } else {
            unsigned short* vtp = ws + (size_t)2 * kBS * kH;
            int h = t >> 1, sc = (t & 1) * 32;
            int bb = m0 >> 11, sl = m0 & 2047;
            #pragma unroll
            for (int u = 0; u < 4; ++u) {
                us8 v = *(const us8*)&smem[h * 72 + sc + u * 8];
                *(us8*)(vtp + ((size_t)bb * kH + h) * kS + sl + sc + u * 8) = v;
            }
        }
    }
}

// ---------------------------------------------------------------------------
// Kernel 2: causal attention — fully WAVE-LOCAL (R5). One 64-lane wave owns
// one 32-row q-slot and iterates ALL its key tiles. No __syncthreads, no
// inter-wave combine; only wave-private Ps LDS (same-wave roundtrip, proven
// R2/R3). Streaming softmax (scores bounded -> exp can't overflow).
// S^T = K·Q^T ; O^T = V^T·P^T ; all operands natural-layout global loads.
// Slot map {63-i, 32+i, 31-i, i} by y>>4: per-CU work constant (130 tiles),
// heavy slots dispatched first.
// ---------------------------------------------------------------------------
__global__ __launch_bounds__(64, 1) void attn(
    const unsigned short* __restrict__ ws, float* __restrict__ out)
{
    __shared__ unsigned short Ps[32 * 36];   // P[q][key], stride 36 (2-way bank only)

    const int L   = threadIdx.x;             // 0..63
    const int l5  = L >> 5;
    const int c32 = L & 31;
    const int b   = blockIdx.x;
    const int g2  = blockIdx.y >> 4, ii = blockIdx.y & 15;
    const int s   = (g2 == 0) ? 63 - ii : (g2 == 1) ? 32 + ii
                  : (g2 == 2) ? 31 - ii : ii;          // bijective onto 0..63

    const unsigned short* qp = ws;
    const unsigned short* kp = ws + (size_t)kBS * kH + (size_t)b * kS * kH;
    const unsigned short* vt = ws + (size_t)2 * kBS * kH + (size_t)b * kH * kS;

    const size_t qrow = (size_t)b * kS + s * 32 + c32;

    // Q B-frags (B-layout: n=lane&31 -> q=c32, k=l5*8+j at k-offset ks*16)
    s8v Qf[8];
    #pragma unroll
    for (int ks = 0; ks < 8; ++ks)
        Qf[ks] = *(const s8v*)(qp + qrow * kH + ks * 16 + l5 * 8);

    f16v O[4];
    #pragma unroll
    for (int nt = 0; nt < 4; ++nt)
        #pragma unroll
        for (int r = 0; r < 16; ++r) O[nt][r] = 0.f;
    float lsum = 0.f;

    // prefetch K tile 0 (A-layout: m=lane&31 -> key row, k=l5*8+j)
    s8v Kf[8];
    #pragma unroll
    for (int ks = 0; ks < 8; ++ks)
        Kf[ks] = *(const s8v*)(kp + (size_t)c32 * kH + ks * 16 + l5 * 8);

    for (int T = 0; T <= s; ++T) {
        const int kb = T * 32;
        // V^T A-frags (m = h within 32-group = c32, k = key)
        s8v Vf[2][4];
        #pragma unroll
        for (int k2 = 0; k2 < 2; ++k2)
            #pragma unroll
            for (int nt = 0; nt < 4; ++nt)
                Vf[k2][nt] = *(const s8v*)(vt + (size_t)(nt * 32 + c32) * kS
                                           + kb + k2 * 16 + l5 * 8);
        // S^T = K Q^T
        f16v Sv;
        #pragma unroll
        for (int r = 0; r < 16; ++r) Sv[r] = 0.f;
        #pragma unroll
        for (int ks = 0; ks < 8; ++ks)
            Sv = __builtin_amdgcn_mfma_f32_32x32x16_bf16(Kf[ks], Qf[ks], Sv, 0, 0, 0);
        // prefetch next K tile
        if (T < s) {
            #pragma unroll
            for (int ks = 0; ks < 8; ++ks)
                Kf[ks] = *(const s8v*)(kp + (size_t)(kb + 32 + c32) * kH + ks * 16 + l5 * 8);
        }
        // mask (diagonal tile) + exp + P store; lane holds 16 keys of q=c32
        const bool dm = (T == s);
        #pragma unroll
        for (int g4 = 0; g4 < 4; ++g4) {
            us4 pk;
            #pragma unroll
            for (int u = 0; u < 4; ++u) {
                int krow = u + 8 * g4 + 4 * l5;       // C-layout row = key
                float v = Sv[g4 * 4 + u];
                if (dm && krow > c32) v = -__builtin_inff();
                float e = __expf(v);
                lsum += e;
                pk[u] = f2bf(e);
            }
            *(us4*)&Ps[c32 * 36 + 8 * g4 + 4 * l5] = pk;
        }
        // O^T += V^T P^T (same-wave LDS roundtrip)
        #pragma unroll
        for (int k2 = 0; k2 < 2; ++k2) {
            us4 plo = *(const us4*)&Ps[c32 * 36 + k2 * 16 + l5 * 8];
            us4 phi = *(const us4*)&Ps[c32 * 36 + k2 * 16 + l5 * 8 + 4];
            us8 pc;
            pc[0]=plo[0]; pc[1]=plo[1]; pc[2]=plo[2]; pc[3]=plo[3];
            pc[4]=phi[0]; pc[5]=phi[1]; pc[6]=phi[2]; pc[7]=phi[3];
            s8v Pb = __builtin_bit_cast(s8v, pc);
            #pragma unroll
            for (int nt = 0; nt < 4; ++nt)
                O[nt] = __builtin_amdgcn_mfma_f32_32x32x16_bf16(Vf[k2][nt], Pb, O[nt], 0, 0, 0);
        }
    }

    // total l for q=c32: combine the two l5 half-sums in-wave
    float lv = lsum + __shfl_xor(lsum, 32);
    const float inv = 1.0f / lv;

    // write out: h = nt*32 + 8*g4 + 4*l5 + u, q = c32
    #pragma unroll
    for (int nt = 0; nt < 4; ++nt)
        #pragma unroll
        for (int g4 = 0; g4 < 4; ++g4) {
            f4v r;
            #pragma unroll
            for (int u = 0; u < 4; ++u) r[u] = O[nt][g4 * 4 + u] * inv;
            *(f4v*)(out + qrow * kH + nt * 32 + 8 * g4 + 4 * l5) = r;
        }
}

extern "C" void kernel_launch(void* const* d_in, const int* in_sizes, int n_in,
                              void* d_out, int out_size, void* d_ws, size_t ws_size,
                              hipStream_t stream) {
    const float* X  = (const float*)d_in[0];
    const float* Wq = (const float*)d_in[1];
    const float* Wk = (const float*)d_in[2];
    const float* Wv = (const float*)d_in[3];
    unsigned short* ws = (unsigned short*)d_ws;          // q | k | v^T bf16 (25.2 MB)
    unsigned short* Wt = ws + (size_t)3 * kBS * kH;      // +768 KB transposed weights
    float* out = (float*)d_out;

    prep_w<<<dim3(3, 16), 256, 0, stream>>>(Wq, Wk, Wv, Wt);
    qkv_gemm<<<dim3(kBS / 64), 256, 0, stream>>>(X, Wt, ws);
    attn<<<dim3(kB, 64), 64, 0, stream>>>(ws, out);
}